// Round 1
// baseline (161.277 us; speedup 1.0000x reference)
//
#include <hip/hip_runtime.h>

// CASSI forward: Y[b,m,no] = sum_l H[m,no-l] * x[b,m,no-l,l], no in [0,542)
// then Y /= max(Y); output = [Y flat | H flat].
// B=8, M=512, L=31, S=1.

#define MDIM   512
#define LBANDS 31
#define WOUT   (MDIM + LBANDS - 1)   // 542
#define BATCH  8

__global__ __launch_bounds__(256) void cassi_forward_kernel(
    const float* __restrict__ x,      // (B, M, M, L)
    const float* __restrict__ Hm,     // (M, M)
    float* __restrict__ Y,            // (B, M, WOUT) -> d_out[0..ysize)
    unsigned int* __restrict__ gmax,  // 1 uint in d_ws, pre-zeroed
    int total)                        // B*M*WOUT
{
    const int idx = blockIdx.x * blockDim.x + threadIdx.x;
    float y = 0.0f;
    if (idx < total) {
        const int no = idx % WOUT;
        const int bm = idx / WOUT;            // b*M + m
        const int m  = bm & (MDIM - 1);
        const float* __restrict__ xrow = x + (long long)bm * (MDIM * LBANDS);
        const float* __restrict__ hrow = Hm + m * MDIM;

        int l0 = no - (MDIM - 1); if (l0 < 0) l0 = 0;
        int l1 = (no < LBANDS - 1) ? no : (LBANDS - 1);
        #pragma unroll 4
        for (int l = l0; l <= l1; ++l) {
            const int n = no - l;
            y = fmaf(hrow[n], xrow[n * LBANDS + l], y);
        }
        Y[idx] = y;
    }

    // Block max reduction (all values >= 0; inactive threads contribute 0).
    float wmax = y;
    #pragma unroll
    for (int off = 32; off > 0; off >>= 1)
        wmax = fmaxf(wmax, __shfl_down(wmax, off, 64));

    __shared__ float smax[4];  // 256 threads = 4 waves
    const int lane = threadIdx.x & 63;
    const int wid  = threadIdx.x >> 6;
    if (lane == 0) smax[wid] = wmax;
    __syncthreads();
    if (threadIdx.x == 0) {
        float bmax = fmaxf(fmaxf(smax[0], smax[1]), fmaxf(smax[2], smax[3]));
        // uint-ordered atomicMax is float-ordered for non-negative floats
        atomicMax(gmax, __float_as_uint(bmax));
    }
}

__global__ __launch_bounds__(256) void cassi_normalize_kernel(
    const float* __restrict__ Hm,             // (M, M) input
    float* __restrict__ out,                  // [Y | H]
    const unsigned int* __restrict__ gmax,
    int ysize, int total)
{
    const int idx = blockIdx.x * blockDim.x + threadIdx.x;
    if (idx >= total) return;
    const float inv = 1.0f / __uint_as_float(*gmax);
    if (idx < ysize) {
        out[idx] *= inv;
    } else {
        out[idx] = Hm[idx - ysize];
    }
}

extern "C" void kernel_launch(void* const* d_in, const int* in_sizes, int n_in,
                              void* d_out, int out_size, void* d_ws, size_t ws_size,
                              hipStream_t stream) {
    const float* x  = (const float*)d_in[0];   // (8, 512, 512, 31, 1)
    const float* Hm = (const float*)d_in[1];   // (1, 512, 512, 1, 1)
    float* out = (float*)d_out;                // [Y (8*512*542) | H (512*512)]
    unsigned int* gmax = (unsigned int*)d_ws;

    const int ysize = BATCH * MDIM * WOUT;     // 2,220,032
    const int total = out_size;                // ysize + 512*512

    // d_ws is poisoned (0xAA) and never re-poisoned: zero the max accumulator
    // every call (async memset is graph-capture safe).
    hipMemsetAsync(d_ws, 0, sizeof(unsigned int), stream);

    cassi_forward_kernel<<<(ysize + 255) / 256, 256, 0, stream>>>(
        x, Hm, out, gmax, ysize);
    cassi_normalize_kernel<<<(total + 255) / 256, 256, 0, stream>>>(
        Hm, out, gmax, ysize, total);
}